// Round 7
// baseline (148.785 us; speedup 1.0000x reference)
//
#include <hip/hip_runtime.h>
#include <hip/hip_bf16.h>
#include <math.h>

#define TT 512
#define CC 1024
#define NH 16
#define NKV 8
#define HD 64
static constexpr float EPS_ = 1e-6f;

typedef short bf16x8 __attribute__((ext_vector_type(8)));
typedef float f32x4 __attribute__((ext_vector_type(4)));

__device__ __forceinline__ ushort f2bf(float f) {
  union { __hip_bfloat16 h; ushort u; } cv;
  cv.h = __float2bfloat16(f);
  return cv.u;
}

__device__ __forceinline__ void gload16(const ushort* g, ushort* l) {
  __builtin_amdgcn_global_load_lds(
      (const __attribute__((address_space(1))) unsigned int*)g,
      (__attribute__((address_space(3))) unsigned int*)l, 16, 0, 0);
}

// ---------------------------------------------------------------------------
// prep: x -> bf16 (same layout); Wq/Wk/Wv/Wo -> transposed bf16 Wt[n][k]
// ---------------------------------------------------------------------------
__global__ __launch_bounds__(256) void prep_kernel(
    const float* __restrict__ x,
    const float* __restrict__ Wq, const float* __restrict__ Wk,
    const float* __restrict__ Wv, const float* __restrict__ Wo,
    ushort* __restrict__ xb, ushort* __restrict__ Wtq, ushort* __restrict__ Wtk,
    ushort* __restrict__ Wtv, ushort* __restrict__ Wto)
{
  int b = blockIdx.x;
  if (b < 256) {
    int base = b * 2048 + threadIdx.x * 8;
    float4 f0 = *reinterpret_cast<const float4*>(&x[base]);
    float4 f1 = *reinterpret_cast<const float4*>(&x[base + 4]);
    union { ushort u[8]; uint4 v; } pk;
    pk.u[0] = f2bf(f0.x); pk.u[1] = f2bf(f0.y); pk.u[2] = f2bf(f0.z); pk.u[3] = f2bf(f0.w);
    pk.u[4] = f2bf(f1.x); pk.u[5] = f2bf(f1.y); pk.u[6] = f2bf(f1.z); pk.u[7] = f2bf(f1.w);
    *reinterpret_cast<uint4*>(&xb[base]) = pk.v;
    return;
  }
  b -= 256;
  const float* W; ushort* Wt; int ldW, tr, tc;
  if (b < 256)      { W = Wq; Wt = Wtq; ldW = 1024; tr = b >> 4;       tc = b & 15; }
  else if (b < 384) { int q = b - 256; W = Wk; Wt = Wtk; ldW = 512; tr = q >> 3; tc = q & 7; }
  else if (b < 512) { int q = b - 384; W = Wv; Wt = Wtv; ldW = 512; tr = q >> 3; tc = q & 7; }
  else              { int q = b - 512; W = Wo; Wt = Wto; ldW = 1024; tr = q >> 4; tc = q & 15; }
  const int k0 = tr * 64, n0 = tc * 64;
  __shared__ float ft[64][65];
  const int t = threadIdx.x;
#pragma unroll
  for (int it = 0; it < 4; ++it) {
    int q = t + it * 256;
    int r = q >> 4, c4 = q & 15;
    float4 f = *reinterpret_cast<const float4*>(&W[(k0 + r) * ldW + n0 + c4 * 4]);
    ft[r][c4 * 4 + 0] = f.x; ft[r][c4 * 4 + 1] = f.y;
    ft[r][c4 * 4 + 2] = f.z; ft[r][c4 * 4 + 3] = f.w;
  }
  __syncthreads();
#pragma unroll
  for (int it = 0; it < 2; ++it) {
    int q = t + it * 256;
    int n = q >> 3, kc = q & 7;
    union { ushort u[8]; uint4 v; } pk;
#pragma unroll
    for (int j = 0; j < 8; ++j) pk.u[j] = f2bf(ft[kc * 8 + j][n]);
    *reinterpret_cast<uint4*>(&Wt[(n0 + n) * 1024 + k0 + kc * 8]) = pk.v;
  }
}

// ---------------------------------------------------------------------------
// bf16 MFMA GEMM: C[64x64 tile] = A[M][1024] @ Bt[N][1024]^T, fp32 out.
// Linear LDS + global_load_lds width-16 staging (no VGPR round-trip).
// ---------------------------------------------------------------------------
__device__ __forceinline__ void mfma_gemm64(
    const ushort* __restrict__ A, const ushort* __restrict__ Bt,
    float* __restrict__ C, int ldC, int row0, int col0)
{
  __shared__ __align__(16) ushort At[64 * 64];
  __shared__ __align__(16) ushort Bs[64 * 64];
  const int tid = threadIdx.x;
  const int lane = tid & 63, w = tid >> 6;
  const int m0 = (w & 1) * 32, n0 = (w >> 1) * 32;
  const int lr = lane & 15, lk = (lane >> 4) * 8;
  f32x4 acc[2][2] = {};
  const int srow = tid >> 3, sc8 = (tid & 7) * 8;
  const ushort* Ap = &A[(row0 + srow) * 1024 + sc8];
  const ushort* Bp = &Bt[(col0 + srow) * 1024 + sc8];
  ushort* Al = &At[tid * 8];
  ushort* Bl = &Bs[tid * 8];

  for (int k0 = 0; k0 < 1024; k0 += 64) {
    __syncthreads();
    gload16(Ap + k0, Al);
    gload16(Ap + 32 * 1024 + k0, Al + 2048);
    gload16(Bp + k0, Bl);
    gload16(Bp + 32 * 1024 + k0, Bl + 2048);
    __syncthreads();
#pragma unroll
    for (int kk = 0; kk < 2; ++kk) {
      bf16x8 af[2], bg[2];
      af[0] = *reinterpret_cast<const bf16x8*>(&At[(m0 + lr) * 64 + kk * 32 + lk]);
      af[1] = *reinterpret_cast<const bf16x8*>(&At[(m0 + 16 + lr) * 64 + kk * 32 + lk]);
      bg[0] = *reinterpret_cast<const bf16x8*>(&Bs[(n0 + lr) * 64 + kk * 32 + lk]);
      bg[1] = *reinterpret_cast<const bf16x8*>(&Bs[(n0 + 16 + lr) * 64 + kk * 32 + lk]);
#pragma unroll
      for (int mi = 0; mi < 2; ++mi)
#pragma unroll
        for (int ni = 0; ni < 2; ++ni)
          acc[mi][ni] = __builtin_amdgcn_mfma_f32_16x16x32_bf16(af[mi], bg[ni], acc[mi][ni], 0, 0, 0);
    }
  }
  const int crow = (lane >> 4) * 4, ccol = lane & 15;
#pragma unroll
  for (int mi = 0; mi < 2; ++mi)
#pragma unroll
    for (int ni = 0; ni < 2; ++ni) {
      int rb = row0 + m0 + mi * 16 + crow;
      int cc = col0 + n0 + ni * 16 + ccol;
#pragma unroll
      for (int r = 0; r < 4; ++r)
        C[(rb + r) * ldC + cc] = acc[mi][ni][r];
    }
}

__global__ __launch_bounds__(256) void qkv_mfma_kernel(
    const ushort* __restrict__ xb,
    const ushort* __restrict__ Wtq, const ushort* __restrict__ Wtk, const ushort* __restrict__ Wtv,
    float* __restrict__ qb, float* __restrict__ kb, float* __restrict__ vb)
{
  int bx = blockIdx.x, by = blockIdx.y;
  if (bx < 16)      mfma_gemm64(xb, Wtq, qb, 1024, by * 64, bx * 64);
  else if (bx < 24) mfma_gemm64(xb, Wtk, kb, 512, by * 64, (bx - 16) * 64);
  else              mfma_gemm64(xb, Wtv, vb, 512, by * 64, (bx - 24) * 64);
}

__global__ __launch_bounds__(256) void out_mfma_kernel(
    const ushort* __restrict__ yb, const ushort* __restrict__ Wto, float* __restrict__ out)
{
  mfma_gemm64(yb, Wto, out, 1024, blockIdx.y * 64, blockIdx.x * 64);
}

// ---------------------------------------------------------------------------
// RoPE + RMS-norm, in place (fp32).
// ---------------------------------------------------------------------------
__global__ __launch_bounds__(256) void rope_rms_kernel(
    float* __restrict__ qb, float* __restrict__ kb,
    const float* __restrict__ cosb, const float* __restrict__ sinb)
{
  int rid = blockIdx.x * 4 + (threadIdx.x >> 6);
  int lane = threadIdx.x & 63;
  float* p; int t;
  if (rid < TT * NH) { t = rid >> 4; p = qb + t * 1024 + (rid & 15) * 64; }
  else { int r2 = rid - TT * NH; t = r2 >> 3; p = kb + t * 512 + (r2 & 7) * 64; }

  float v = p[lane];
  float part = __shfl_xor(v, 32);
  int f = lane & 31;
  float c = cosb[t * 32 + f], s = sinb[t * 32 + f];
  float o = (lane < 32) ? (v * c - part * s) : (part * s + v * c);
  float ss = o * o;
#pragma unroll
  for (int off = 32; off; off >>= 1) ss += __shfl_xor(ss, off);
  float r = rsqrtf(ss * (1.0f / 64.0f) + EPS_);
  p[lane] = o * r;
}

// ---------------------------------------------------------------------------
// Transpose normalized K: kb[t][g*64+d] -> kt[g][d][t]  (g-major, 64x512).
// Grid 64 = (g, t-tile). Pad-65 LDS: 2-way conflicts max (free).
// ---------------------------------------------------------------------------
__global__ __launch_bounds__(256) void ktrans_kernel(
    const float* __restrict__ kb, float* __restrict__ kt)
{
  __shared__ float ft[64][65];
  const int b = blockIdx.x;
  const int g = b >> 3, t0 = (b & 7) * 64;
  const int tid = threadIdx.x;
  const int r16 = tid >> 4, c4 = tid & 15;
#pragma unroll
  for (int it = 0; it < 4; ++it) {
    int row = r16 + it * 16;
    float4 f = *reinterpret_cast<const float4*>(&kb[(t0 + row) * 512 + g * 64 + c4 * 4]);
    ft[row][c4 * 4 + 0] = f.x; ft[row][c4 * 4 + 1] = f.y;
    ft[row][c4 * 4 + 2] = f.z; ft[row][c4 * 4 + 3] = f.w;
  }
  __syncthreads();
#pragma unroll
  for (int it = 0; it < 4; ++it) {
    int d = r16 + it * 16;
    float4 o = make_float4(ft[c4 * 4 + 0][d], ft[c4 * 4 + 1][d],
                           ft[c4 * 4 + 2][d], ft[c4 * 4 + 3][d]);
    *reinterpret_cast<float4*>(&kt[g * 32768 + d * 512 + t0 + c4 * 4]) = o;
  }
}

// ---------------------------------------------------------------------------
// Tropical causal attention, v6: barrier-free balanced split-K.
// Unit = (head h, 8-row q-chunk c8, j-tile jt<=c8/8): 4608 identical units,
// one per wave; 1152 blocks x 4 waves. No __syncthreads anywhere.
// K columns from kt (coalesced L2), V rows direct from global (coalesced),
// q broadcast direct from global. LDS = pS only (p transpose for PV).
// Deferred softmax (scores bounded by RMS-norm); partial acc/lsum -> ws.
// ---------------------------------------------------------------------------
__global__ __launch_bounds__(256) void attn_part_kernel(
    const float* __restrict__ qb, const float* __restrict__ kt,
    const float* __restrict__ vb, float* __restrict__ pacc,
    float* __restrict__ plsum)
{
  __shared__ __align__(16) float pS[4][8][64];
  const int tid = threadIdx.x;
  const int w = tid >> 6, lane = tid & 63;
  const int u = blockIdx.x * 4 + w;
  const int h = u / 288;
  const int r = u - h * 288;
  // A-band: units with c8 in [8A,8A+7] start at 4A(A+1)
  const int A = (r >= 8) + (r >= 24) + (r >= 48) + (r >= 80) +
                (r >= 120) + (r >= 168) + (r >= 224);
  const int rb = r - 4 * A * (A + 1);
  const int c8 = 8 * A + rb / (A + 1);
  const int jt = rb % (A + 1);
  const int g = h >> 1;
  const int i0 = c8 * 8;
  const int j0 = jt * 64;
  const bool diag = (jt == A);

  // K column block (lane = j) from kt, coalesced
  float kreg[64];
  const float* ktp = &kt[g * 32768 + j0 + lane];
#pragma unroll
  for (int d = 0; d < 64; ++d) kreg[d] = ktp[d * 512];

  // scores + exp (deferred softmax)
  float p[8];
  const float* qp = &qb[i0 * 1024 + h * 64];
#pragma unroll
  for (int q = 0; q < 8; ++q) {
    float s0 = -INFINITY, s1 = -INFINITY;
#pragma unroll
    for (int d4 = 0; d4 < 16; ++d4) {
      float4 qv = *reinterpret_cast<const float4*>(qp + q * 1024 + d4 * 4);
      s0 = fmaxf(fmaxf(s0, qv.x + kreg[d4 * 4 + 0]), qv.y + kreg[d4 * 4 + 1]);
      s1 = fmaxf(fmaxf(s1, qv.z + kreg[d4 * 4 + 2]), qv.w + kreg[d4 * 4 + 3]);
    }
    float s = fmaxf(s0, s1);
    if (diag && (j0 + lane > i0 + q)) s = -INFINITY;
    p[q] = __expf(s);
    pS[w][q][lane] = p[q];
  }

  // PV: lane = d; V rows direct from global, p broadcast from LDS
  float acc[8] = {0.f, 0.f, 0.f, 0.f, 0.f, 0.f, 0.f, 0.f};
  const float* vp = &vb[j0 * 512 + g * 64 + lane];
#pragma unroll
  for (int j4 = 0; j4 < 16; ++j4) {
    float vv0 = vp[(j4 * 4 + 0) * 512];
    float vv1 = vp[(j4 * 4 + 1) * 512];
    float vv2 = vp[(j4 * 4 + 2) * 512];
    float vv3 = vp[(j4 * 4 + 3) * 512];
#pragma unroll
    for (int q = 0; q < 8; ++q) {
      float4 pv = *reinterpret_cast<const float4*>(&pS[w][q][j4 * 4]);
      acc[q] = fmaf(pv.x, vv0, fmaf(pv.y, vv1, fmaf(pv.z, vv2, fmaf(pv.w, vv3, acc[q]))));
    }
  }

  // per-row partial denominators (reduce retained p), then store partials
  float lsel = 0.f;
#pragma unroll
  for (int q = 0; q < 8; ++q) {
    float l = p[q];
#pragma unroll
    for (int off = 32; off; off >>= 1) l += __shfl_xor(l, off);
    if (lane == q) lsel = l;
  }
  if (lane < 8) plsum[u * 8 + lane] = lsel;
#pragma unroll
  for (int q = 0; q < 8; ++q)
    pacc[u * 512 + q * 64 + lane] = acc[q];
}

// ---------------------------------------------------------------------------
// Combine split-K partials: y = (sum acc)/(sum l), write bf16.
// Grid 1024 = (h, c8).
// ---------------------------------------------------------------------------
__global__ __launch_bounds__(256) void attn_combine_kernel(
    const float* __restrict__ pacc, const float* __restrict__ plsum,
    ushort* __restrict__ yb)
{
  const int b = blockIdx.x;
  const int h = b >> 6, c8 = b & 63;
  const int A = c8 >> 3;
  const int nj = A + 1;
  const int u0 = h * 288 + 4 * A * (A + 1) + (c8 & 7) * nj;
  const int tid = threadIdx.x;
#pragma unroll
  for (int e = tid; e < 512; e += 256) {
    const int q = e >> 6, d = e & 63;
    float a = 0.f, l = 0.f;
    for (int jt = 0; jt < nj; ++jt) {
      a += pacc[(u0 + jt) * 512 + q * 64 + d];
      l += plsum[(u0 + jt) * 8 + q];
    }
    yb[(c8 * 8 + q) * 1024 + h * 64 + d] = f2bf(a / l);
  }
}

// ---------------------------------------------------------------------------
extern "C" void kernel_launch(void* const* d_in, const int* in_sizes, int n_in,
                              void* d_out, int out_size, void* d_ws, size_t ws_size,
                              hipStream_t stream) {
  const float* x    = (const float*)d_in[0];
  const float* cosb = (const float*)d_in[1];
  const float* sinb = (const float*)d_in[2];
  const float* Wq   = (const float*)d_in[3];
  const float* Wk   = (const float*)d_in[4];
  const float* Wv   = (const float*)d_in[5];
  const float* Wo   = (const float*)d_in[6];
  float* out = (float*)d_out;

  float* wsf = (float*)d_ws;
  float* qbuf = wsf;                      // 512x1024 f32
  float* kbuf = qbuf + TT * CC;           // 512x512  f32
  float* vbuf = kbuf + TT * 512;          // 512x512  f32
  float* ktb  = vbuf + TT * 512;          // 8x64x512 f32 (K^T per kv head)
  float* pacc = ktb + 8 * 64 * 512;       // 4608x512 f32 partial acc
  float* plsum = pacc + 4608 * 512;       // 4608x8 f32 partial lsum
  ushort* wsu = (ushort*)(plsum + 4608 * 8);
  ushort* xb  = wsu;                      // 512x1024 bf16
  ushort* yb  = xb + TT * CC;             // 512x1024 bf16
  ushort* Wtq = yb + TT * CC;             // 1024x1024 bf16
  ushort* Wtk = Wtq + CC * CC;            // 512x1024 bf16
  ushort* Wtv = Wtk + 512 * CC;           // 512x1024 bf16
  ushort* Wto = Wtv + 512 * CC;           // 1024x1024 bf16

  prep_kernel<<<dim3(1024), 256, 0, stream>>>(x, Wq, Wk, Wv, Wo, xb, Wtq, Wtk, Wtv, Wto);
  qkv_mfma_kernel<<<dim3(32, 8), 256, 0, stream>>>(xb, Wtq, Wtk, Wtv, qbuf, kbuf, vbuf);
  rope_rms_kernel<<<dim3((TT * NH + TT * NKV) / 4), 256, 0, stream>>>(qbuf, kbuf, cosb, sinb);
  ktrans_kernel<<<dim3(64), 256, 0, stream>>>(kbuf, ktb);
  attn_part_kernel<<<dim3(1152), 256, 0, stream>>>(qbuf, ktb, vbuf, pacc, plsum);
  attn_combine_kernel<<<dim3(1024), 256, 0, stream>>>(pacc, plsum, yb);
  out_mfma_kernel<<<dim3(16, 8), 256, 0, stream>>>(yb, Wto, out);
}

// Round 8
// 91.846 us; speedup vs baseline: 1.6199x; 1.6199x over previous
//
#include <hip/hip_runtime.h>
#include <hip/hip_bf16.h>
#include <math.h>

#define TT 512
#define CC 1024
#define NH 16
#define NKV 8
#define HD 64
static constexpr float EPS_ = 1e-6f;

typedef short bf16x8 __attribute__((ext_vector_type(8)));
typedef float f32x4 __attribute__((ext_vector_type(4)));

__device__ __forceinline__ ushort f2bf(float f) {
  union { __hip_bfloat16 h; ushort u; } cv;
  cv.h = __float2bfloat16(f);
  return cv.u;
}

__device__ __forceinline__ void gload16(const ushort* g, ushort* l) {
  __builtin_amdgcn_global_load_lds(
      (const __attribute__((address_space(1))) unsigned int*)g,
      (__attribute__((address_space(3))) unsigned int*)l, 16, 0, 0);
}

// ---------------------------------------------------------------------------
// prep: x -> bf16 (same layout); Wq/Wk/Wv/Wo -> transposed bf16 Wt[n][k]
// ---------------------------------------------------------------------------
__global__ __launch_bounds__(256) void prep_kernel(
    const float* __restrict__ x,
    const float* __restrict__ Wq, const float* __restrict__ Wk,
    const float* __restrict__ Wv, const float* __restrict__ Wo,
    ushort* __restrict__ xb, ushort* __restrict__ Wtq, ushort* __restrict__ Wtk,
    ushort* __restrict__ Wtv, ushort* __restrict__ Wto)
{
  int b = blockIdx.x;
  if (b < 256) {
    int base = b * 2048 + threadIdx.x * 8;
    float4 f0 = *reinterpret_cast<const float4*>(&x[base]);
    float4 f1 = *reinterpret_cast<const float4*>(&x[base + 4]);
    union { ushort u[8]; uint4 v; } pk;
    pk.u[0] = f2bf(f0.x); pk.u[1] = f2bf(f0.y); pk.u[2] = f2bf(f0.z); pk.u[3] = f2bf(f0.w);
    pk.u[4] = f2bf(f1.x); pk.u[5] = f2bf(f1.y); pk.u[6] = f2bf(f1.z); pk.u[7] = f2bf(f1.w);
    *reinterpret_cast<uint4*>(&xb[base]) = pk.v;
    return;
  }
  b -= 256;
  const float* W; ushort* Wt; int ldW, tr, tc;
  if (b < 256)      { W = Wq; Wt = Wtq; ldW = 1024; tr = b >> 4;       tc = b & 15; }
  else if (b < 384) { int q = b - 256; W = Wk; Wt = Wtk; ldW = 512; tr = q >> 3; tc = q & 7; }
  else if (b < 512) { int q = b - 384; W = Wv; Wt = Wtv; ldW = 512; tr = q >> 3; tc = q & 7; }
  else              { int q = b - 512; W = Wo; Wt = Wto; ldW = 1024; tr = q >> 4; tc = q & 15; }
  const int k0 = tr * 64, n0 = tc * 64;
  __shared__ float ft[64][65];
  const int t = threadIdx.x;
#pragma unroll
  for (int it = 0; it < 4; ++it) {
    int q = t + it * 256;
    int r = q >> 4, c4 = q & 15;
    float4 f = *reinterpret_cast<const float4*>(&W[(k0 + r) * ldW + n0 + c4 * 4]);
    ft[r][c4 * 4 + 0] = f.x; ft[r][c4 * 4 + 1] = f.y;
    ft[r][c4 * 4 + 2] = f.z; ft[r][c4 * 4 + 3] = f.w;
  }
  __syncthreads();
#pragma unroll
  for (int it = 0; it < 2; ++it) {
    int q = t + it * 256;
    int n = q >> 3, kc = q & 7;
    union { ushort u[8]; uint4 v; } pk;
#pragma unroll
    for (int j = 0; j < 8; ++j) pk.u[j] = f2bf(ft[kc * 8 + j][n]);
    *reinterpret_cast<uint4*>(&Wt[(n0 + n) * 1024 + k0 + kc * 8]) = pk.v;
  }
}

// ---------------------------------------------------------------------------
// bf16 MFMA GEMM: C[64x64 tile] = A[M][1024] @ Bt[N][1024]^T, fp32 out.
// Linear LDS + global_load_lds width-16 staging.
// ---------------------------------------------------------------------------
__device__ __forceinline__ void mfma_gemm64(
    const ushort* __restrict__ A, const ushort* __restrict__ Bt,
    float* __restrict__ C, int ldC, int row0, int col0)
{
  __shared__ __align__(16) ushort At[64 * 64];
  __shared__ __align__(16) ushort Bs[64 * 64];
  const int tid = threadIdx.x;
  const int lane = tid & 63, w = tid >> 6;
  const int m0 = (w & 1) * 32, n0 = (w >> 1) * 32;
  const int lr = lane & 15, lk = (lane >> 4) * 8;
  f32x4 acc[2][2] = {};
  const int srow = tid >> 3, sc8 = (tid & 7) * 8;
  const ushort* Ap = &A[(row0 + srow) * 1024 + sc8];
  const ushort* Bp = &Bt[(col0 + srow) * 1024 + sc8];
  ushort* Al = &At[tid * 8];
  ushort* Bl = &Bs[tid * 8];

  for (int k0 = 0; k0 < 1024; k0 += 64) {
    __syncthreads();
    gload16(Ap + k0, Al);
    gload16(Ap + 32 * 1024 + k0, Al + 2048);
    gload16(Bp + k0, Bl);
    gload16(Bp + 32 * 1024 + k0, Bl + 2048);
    __syncthreads();
#pragma unroll
    for (int kk = 0; kk < 2; ++kk) {
      bf16x8 af[2], bg[2];
      af[0] = *reinterpret_cast<const bf16x8*>(&At[(m0 + lr) * 64 + kk * 32 + lk]);
      af[1] = *reinterpret_cast<const bf16x8*>(&At[(m0 + 16 + lr) * 64 + kk * 32 + lk]);
      bg[0] = *reinterpret_cast<const bf16x8*>(&Bs[(n0 + lr) * 64 + kk * 32 + lk]);
      bg[1] = *reinterpret_cast<const bf16x8*>(&Bs[(n0 + 16 + lr) * 64 + kk * 32 + lk]);
#pragma unroll
      for (int mi = 0; mi < 2; ++mi)
#pragma unroll
        for (int ni = 0; ni < 2; ++ni)
          acc[mi][ni] = __builtin_amdgcn_mfma_f32_16x16x32_bf16(af[mi], bg[ni], acc[mi][ni], 0, 0, 0);
    }
  }
  const int crow = (lane >> 4) * 4, ccol = lane & 15;
#pragma unroll
  for (int mi = 0; mi < 2; ++mi)
#pragma unroll
    for (int ni = 0; ni < 2; ++ni) {
      int rb = row0 + m0 + mi * 16 + crow;
      int cc = col0 + n0 + ni * 16 + ccol;
#pragma unroll
      for (int r = 0; r < 4; ++r)
        C[(rb + r) * ldC + cc] = acc[mi][ni][r];
    }
}

__global__ __launch_bounds__(256) void qkv_mfma_kernel(
    const ushort* __restrict__ xb,
    const ushort* __restrict__ Wtq, const ushort* __restrict__ Wtk, const ushort* __restrict__ Wtv,
    float* __restrict__ qb, float* __restrict__ kb, float* __restrict__ vb)
{
  int bx = blockIdx.x, by = blockIdx.y;
  if (bx < 16)      mfma_gemm64(xb, Wtq, qb, 1024, by * 64, bx * 64);
  else if (bx < 24) mfma_gemm64(xb, Wtk, kb, 512, by * 64, (bx - 16) * 64);
  else              mfma_gemm64(xb, Wtv, vb, 512, by * 64, (bx - 24) * 64);
}

__global__ __launch_bounds__(256) void out_mfma_kernel(
    const ushort* __restrict__ yb, const ushort* __restrict__ Wto, float* __restrict__ out)
{
  mfma_gemm64(yb, Wto, out, 1024, blockIdx.y * 64, blockIdx.x * 64);
}

// ---------------------------------------------------------------------------
// RoPE + RMS-norm, in place (fp32).
// ---------------------------------------------------------------------------
__global__ __launch_bounds__(256) void rope_rms_kernel(
    float* __restrict__ qb, float* __restrict__ kb,
    const float* __restrict__ cosb, const float* __restrict__ sinb)
{
  int rid = blockIdx.x * 4 + (threadIdx.x >> 6);
  int lane = threadIdx.x & 63;
  float* p; int t;
  if (rid < TT * NH) { t = rid >> 4; p = qb + t * 1024 + (rid & 15) * 64; }
  else { int r2 = rid - TT * NH; t = r2 >> 3; p = kb + t * 512 + (r2 & 7) * 64; }

  float v = p[lane];
  float part = __shfl_xor(v, 32);
  int f = lane & 31;
  float c = cosb[t * 32 + f], s = sinb[t * 32 + f];
  float o = (lane < 32) ? (v * c - part * s) : (part * s + v * c);
  float ss = o * o;
#pragma unroll
  for (int off = 32; off; off >>= 1) ss += __shfl_xor(ss, off);
  float r = rsqrtf(ss * (1.0f / 64.0f) + EPS_);
  p[lane] = o * r;
}

// ---------------------------------------------------------------------------
// Tropical causal attention, v7: uniform-unit split-K, R6's proven body.
// Unit (block) = (head h, 16-row q-chunk c, ONE 64-j tile jt<=c/4).
// Per h: sum_c (c/4+1) = 144 units -> 2304 identical blocks.
// 4 waves x 4 q-rows. Deferred softmax (scores bounded by RMS-norm).
// Only kreg[64] in registers (no spill); V and p via LDS as in R6.
// Partials (acc, lsum) -> ws; combined by attn_combine.
// Unit packing per h: band A=c/4 starts at 2A(A+1); within band,
// offset (c&3)*(A+1) + jt.
// ---------------------------------------------------------------------------
__global__ __launch_bounds__(256) void attn_part_kernel(
    const float* __restrict__ qb, const float* __restrict__ kb,
    const float* __restrict__ vb, float* __restrict__ pacc,
    float* __restrict__ plsum)
{
  __shared__ float kS[64][76];
  __shared__ float vS[64][76];
  __shared__ __align__(16) float qS[16][64];
  __shared__ __align__(16) float pS[4][4][64];

  const int tid = threadIdx.x;
  const int w = tid >> 6, lane = tid & 63;
  const int u = blockIdx.x;
  const int h = u / 144;
  const int r = u - h * 144;
  const int A = (r >= 4) + (r >= 12) + (r >= 24) + (r >= 40) +
                (r >= 60) + (r >= 84) + (r >= 112);
  const int rb = r - 2 * A * (A + 1);
  const int cq = rb / (A + 1);           // c & 3
  const int c = 4 * A + cq;
  const int jt = rb - cq * (A + 1);
  const int g = h >> 1;
  const int i0 = c * 16;
  const int j0 = jt * 64;
  const bool diag = (jt == A);

  // stage q (16 rows of head h)
  {
    int r16 = tid >> 4, c4 = tid & 15;
    *reinterpret_cast<float4*>(&qS[r16][c4 * 4]) =
        *reinterpret_cast<const float4*>(&qb[(i0 + r16) * 1024 + h * 64 + c4 * 4]);
  }
  // stage K,V tile (row-major, coalesced)
#pragma unroll
  for (int it = 0; it < 4; ++it) {
    int s = tid + it * 256;
    int rr = s >> 4, c4 = s & 15;
    *reinterpret_cast<float4*>(&kS[rr][c4 * 4]) =
        *reinterpret_cast<const float4*>(&kb[(j0 + rr) * 512 + g * 64 + c4 * 4]);
    *reinterpret_cast<float4*>(&vS[rr][c4 * 4]) =
        *reinterpret_cast<const float4*>(&vb[(j0 + rr) * 512 + g * 64 + c4 * 4]);
  }
  __syncthreads();

  // K row (j = j0+lane) into registers
  float kreg[64];
#pragma unroll
  for (int d4 = 0; d4 < 16; ++d4)
    *reinterpret_cast<float4*>(&kreg[d4 * 4]) =
        *reinterpret_cast<const float4*>(&kS[lane][d4 * 4]);

  // scores + exp (deferred softmax: no reduces here)
  float p[4];
#pragma unroll
  for (int q = 0; q < 4; ++q) {
    const int i = i0 + 4 * w + q;
    const float4* q4 = reinterpret_cast<const float4*>(qS[4 * w + q]);
    float s0 = -INFINITY, s1 = -INFINITY;
#pragma unroll
    for (int d4 = 0; d4 < 16; ++d4) {
      float4 qv = q4[d4];
      s0 = fmaxf(fmaxf(s0, qv.x + kreg[d4 * 4 + 0]), qv.y + kreg[d4 * 4 + 1]);
      s1 = fmaxf(fmaxf(s1, qv.z + kreg[d4 * 4 + 2]), qv.w + kreg[d4 * 4 + 3]);
    }
    float s = fmaxf(s0, s1);
    if (diag && (j0 + lane > i)) s = -INFINITY;
    p[q] = __expf(s);
    pS[w][q][lane] = p[q];                // same-wave RAW (in-order DS pipe)
  }

  // PV: outer j4; V column element read once, shared by 4 q-rows
  float acc[4] = {0.f, 0.f, 0.f, 0.f};
#pragma unroll
  for (int j4 = 0; j4 < 16; ++j4) {
    union { float4 v; float f[4]; } p0, p1, p2, p3;
    p0.v = *reinterpret_cast<const float4*>(&pS[w][0][j4 * 4]);
    p1.v = *reinterpret_cast<const float4*>(&pS[w][1][j4 * 4]);
    p2.v = *reinterpret_cast<const float4*>(&pS[w][2][j4 * 4]);
    p3.v = *reinterpret_cast<const float4*>(&pS[w][3][j4 * 4]);
#pragma unroll
    for (int uu = 0; uu < 4; ++uu) {
      float vv = vS[j4 * 4 + uu][lane];   // conflict-free: lanes consecutive
      acc[0] = fmaf(p0.f[uu], vv, acc[0]);
      acc[1] = fmaf(p1.f[uu], vv, acc[1]);
      acc[2] = fmaf(p2.f[uu], vv, acc[2]);
      acc[3] = fmaf(p3.f[uu], vv, acc[3]);
    }
  }

  // per-row partial denominators; store partials
  float lsel = 0.f;
#pragma unroll
  for (int q = 0; q < 4; ++q) {
    float l = p[q];
#pragma unroll
    for (int off = 32; off; off >>= 1) l += __shfl_xor(l, off);
    if (lane == q) lsel = l;
  }
  if (lane < 4) plsum[u * 16 + 4 * w + lane] = lsel;
#pragma unroll
  for (int q = 0; q < 4; ++q)
    pacc[u * 1024 + (4 * w + q) * 64 + lane] = acc[q];
}

// ---------------------------------------------------------------------------
// Combine split-K partials: y = (sum acc)/(sum l), write bf16.
// Grid 512 = (h, c).
// ---------------------------------------------------------------------------
__global__ __launch_bounds__(256) void attn_combine_kernel(
    const float* __restrict__ pacc, const float* __restrict__ plsum,
    ushort* __restrict__ yb)
{
  const int b = blockIdx.x;
  const int h = b >> 5, c = b & 31;
  const int A = c >> 2;
  const int nj = A + 1;
  const int u0 = h * 144 + 2 * A * (A + 1) + (c & 3) * nj;
  const int tid = threadIdx.x;
#pragma unroll
  for (int e = tid; e < 1024; e += 256) {
    const int row = e >> 6, d = e & 63;
    float a = 0.f, l = 0.f;
    for (int jt = 0; jt < nj; ++jt) {
      a += pacc[(u0 + jt) * 1024 + e];
      l += plsum[(u0 + jt) * 16 + row];
    }
    yb[(c * 16 + row) * 1024 + h * 64 + d] = f2bf(a / l);
  }
}

// ---------------------------------------------------------------------------
extern "C" void kernel_launch(void* const* d_in, const int* in_sizes, int n_in,
                              void* d_out, int out_size, void* d_ws, size_t ws_size,
                              hipStream_t stream) {
  const float* x    = (const float*)d_in[0];
  const float* cosb = (const float*)d_in[1];
  const float* sinb = (const float*)d_in[2];
  const float* Wq   = (const float*)d_in[3];
  const float* Wk   = (const float*)d_in[4];
  const float* Wv   = (const float*)d_in[5];
  const float* Wo   = (const float*)d_in[6];
  float* out = (float*)d_out;

  float* wsf = (float*)d_ws;
  float* qbuf = wsf;                      // 512x1024 f32
  float* kbuf = qbuf + TT * CC;           // 512x512  f32
  float* vbuf = kbuf + TT * 512;          // 512x512  f32
  float* pacc = vbuf + TT * 512;          // 2304x1024 f32 partial acc
  float* plsum = pacc + 2304 * 1024;      // 2304x16 f32 partial lsum
  ushort* wsu = (ushort*)(plsum + 2304 * 16);
  ushort* xb  = wsu;                      // 512x1024 bf16
  ushort* yb  = xb + TT * CC;             // 512x1024 bf16
  ushort* Wtq = yb + TT * CC;             // 1024x1024 bf16
  ushort* Wtk = Wtq + CC * CC;            // 512x1024 bf16
  ushort* Wtv = Wtk + 512 * CC;           // 512x1024 bf16
  ushort* Wto = Wtv + 512 * CC;           // 1024x1024 bf16

  prep_kernel<<<dim3(1024), 256, 0, stream>>>(x, Wq, Wk, Wv, Wo, xb, Wtq, Wtk, Wtv, Wto);
  qkv_mfma_kernel<<<dim3(32, 8), 256, 0, stream>>>(xb, Wtq, Wtk, Wtv, qbuf, kbuf, vbuf);
  rope_rms_kernel<<<dim3((TT * NH + TT * NKV) / 4), 256, 0, stream>>>(qbuf, kbuf, cosb, sinb);
  attn_part_kernel<<<dim3(2304), 256, 0, stream>>>(qbuf, kbuf, vbuf, pacc, plsum);
  attn_combine_kernel<<<dim3(512), 256, 0, stream>>>(pacc, plsum, yb);
  out_mfma_kernel<<<dim3(16, 8), 256, 0, stream>>>(yb, Wto, out);
}

// Round 9
// 85.784 us; speedup vs baseline: 1.7344x; 1.0707x over previous
//
#include <hip/hip_runtime.h>
#include <hip/hip_bf16.h>
#include <math.h>

#define TT 512
#define CC 1024
#define NH 16
#define NKV 8
#define HD 64
static constexpr float EPS_ = 1e-6f;

typedef short bf16x8 __attribute__((ext_vector_type(8)));
typedef float f32x4 __attribute__((ext_vector_type(4)));

__device__ __forceinline__ ushort f2bf(float f) {
  union { __hip_bfloat16 h; ushort u; } cv;
  cv.h = __float2bfloat16(f);
  return cv.u;
}

__device__ __forceinline__ void gload16(const ushort* g, ushort* l) {
  __builtin_amdgcn_global_load_lds(
      (const __attribute__((address_space(1))) unsigned int*)g,
      (__attribute__((address_space(3))) unsigned int*)l, 16, 0, 0);
}

// ---------------------------------------------------------------------------
// prep: x -> bf16 (same layout); Wq/Wk/Wv/Wo -> transposed bf16 Wt[n][k]
// ---------------------------------------------------------------------------
__global__ __launch_bounds__(256) void prep_kernel(
    const float* __restrict__ x,
    const float* __restrict__ Wq, const float* __restrict__ Wk,
    const float* __restrict__ Wv, const float* __restrict__ Wo,
    ushort* __restrict__ xb, ushort* __restrict__ Wtq, ushort* __restrict__ Wtk,
    ushort* __restrict__ Wtv, ushort* __restrict__ Wto)
{
  int b = blockIdx.x;
  if (b < 256) {
    int base = b * 2048 + threadIdx.x * 8;
    float4 f0 = *reinterpret_cast<const float4*>(&x[base]);
    float4 f1 = *reinterpret_cast<const float4*>(&x[base + 4]);
    union { ushort u[8]; uint4 v; } pk;
    pk.u[0] = f2bf(f0.x); pk.u[1] = f2bf(f0.y); pk.u[2] = f2bf(f0.z); pk.u[3] = f2bf(f0.w);
    pk.u[4] = f2bf(f1.x); pk.u[5] = f2bf(f1.y); pk.u[6] = f2bf(f1.z); pk.u[7] = f2bf(f1.w);
    *reinterpret_cast<uint4*>(&xb[base]) = pk.v;
    return;
  }
  b -= 256;
  const float* W; ushort* Wt; int ldW, tr, tc;
  if (b < 256)      { W = Wq; Wt = Wtq; ldW = 1024; tr = b >> 4;       tc = b & 15; }
  else if (b < 384) { int q = b - 256; W = Wk; Wt = Wtk; ldW = 512; tr = q >> 3; tc = q & 7; }
  else if (b < 512) { int q = b - 384; W = Wv; Wt = Wtv; ldW = 512; tr = q >> 3; tc = q & 7; }
  else              { int q = b - 512; W = Wo; Wt = Wto; ldW = 1024; tr = q >> 4; tc = q & 15; }
  const int k0 = tr * 64, n0 = tc * 64;
  __shared__ float ft[64][65];
  const int t = threadIdx.x;
#pragma unroll
  for (int it = 0; it < 4; ++it) {
    int q = t + it * 256;
    int r = q >> 4, c4 = q & 15;
    float4 f = *reinterpret_cast<const float4*>(&W[(k0 + r) * ldW + n0 + c4 * 4]);
    ft[r][c4 * 4 + 0] = f.x; ft[r][c4 * 4 + 1] = f.y;
    ft[r][c4 * 4 + 2] = f.z; ft[r][c4 * 4 + 3] = f.w;
  }
  __syncthreads();
#pragma unroll
  for (int it = 0; it < 2; ++it) {
    int q = t + it * 256;
    int n = q >> 3, kc = q & 7;
    union { ushort u[8]; uint4 v; } pk;
#pragma unroll
    for (int j = 0; j < 8; ++j) pk.u[j] = f2bf(ft[kc * 8 + j][n]);
    *reinterpret_cast<uint4*>(&Wt[(n0 + n) * 1024 + k0 + kc * 8]) = pk.v;
  }
}

// ---------------------------------------------------------------------------
// bf16 MFMA GEMM: C[64x64 tile] = A[M][1024] @ Bt[N][1024]^T, fp32 out.
// ---------------------------------------------------------------------------
__device__ __forceinline__ void mfma_gemm64(
    const ushort* __restrict__ A, const ushort* __restrict__ Bt,
    float* __restrict__ C, int ldC, int row0, int col0)
{
  __shared__ __align__(16) ushort At[64 * 64];
  __shared__ __align__(16) ushort Bs[64 * 64];
  const int tid = threadIdx.x;
  const int lane = tid & 63, w = tid >> 6;
  const int m0 = (w & 1) * 32, n0 = (w >> 1) * 32;
  const int lr = lane & 15, lk = (lane >> 4) * 8;
  f32x4 acc[2][2] = {};
  const int srow = tid >> 3, sc8 = (tid & 7) * 8;
  const ushort* Ap = &A[(row0 + srow) * 1024 + sc8];
  const ushort* Bp = &Bt[(col0 + srow) * 1024 + sc8];
  ushort* Al = &At[tid * 8];
  ushort* Bl = &Bs[tid * 8];

  for (int k0 = 0; k0 < 1024; k0 += 64) {
    __syncthreads();
    gload16(Ap + k0, Al);
    gload16(Ap + 32 * 1024 + k0, Al + 2048);
    gload16(Bp + k0, Bl);
    gload16(Bp + 32 * 1024 + k0, Bl + 2048);
    __syncthreads();
#pragma unroll
    for (int kk = 0; kk < 2; ++kk) {
      bf16x8 af[2], bg[2];
      af[0] = *reinterpret_cast<const bf16x8*>(&At[(m0 + lr) * 64 + kk * 32 + lk]);
      af[1] = *reinterpret_cast<const bf16x8*>(&At[(m0 + 16 + lr) * 64 + kk * 32 + lk]);
      bg[0] = *reinterpret_cast<const bf16x8*>(&Bs[(n0 + lr) * 64 + kk * 32 + lk]);
      bg[1] = *reinterpret_cast<const bf16x8*>(&Bs[(n0 + 16 + lr) * 64 + kk * 32 + lk]);
#pragma unroll
      for (int mi = 0; mi < 2; ++mi)
#pragma unroll
        for (int ni = 0; ni < 2; ++ni)
          acc[mi][ni] = __builtin_amdgcn_mfma_f32_16x16x32_bf16(af[mi], bg[ni], acc[mi][ni], 0, 0, 0);
    }
  }
  const int crow = (lane >> 4) * 4, ccol = lane & 15;
#pragma unroll
  for (int mi = 0; mi < 2; ++mi)
#pragma unroll
    for (int ni = 0; ni < 2; ++ni) {
      int rb = row0 + m0 + mi * 16 + crow;
      int cc = col0 + n0 + ni * 16 + ccol;
#pragma unroll
      for (int r = 0; r < 4; ++r)
        C[(rb + r) * ldC + cc] = acc[mi][ni][r];
    }
}

__global__ __launch_bounds__(256) void qkv_mfma_kernel(
    const ushort* __restrict__ xb,
    const ushort* __restrict__ Wtq, const ushort* __restrict__ Wtk, const ushort* __restrict__ Wtv,
    float* __restrict__ qb, float* __restrict__ kb, float* __restrict__ vb)
{
  int bx = blockIdx.x, by = blockIdx.y;
  if (bx < 16)      mfma_gemm64(xb, Wtq, qb, 1024, by * 64, bx * 64);
  else if (bx < 24) mfma_gemm64(xb, Wtk, kb, 512, by * 64, (bx - 16) * 64);
  else              mfma_gemm64(xb, Wtv, vb, 512, by * 64, (bx - 24) * 64);
}

__global__ __launch_bounds__(256) void out_mfma_kernel(
    const ushort* __restrict__ yb, const ushort* __restrict__ Wto, float* __restrict__ out)
{
  mfma_gemm64(yb, Wto, out, 1024, blockIdx.y * 64, blockIdx.x * 64);
}

// ---------------------------------------------------------------------------
// RoPE + RMS-norm, in place (fp32).
// ---------------------------------------------------------------------------
__global__ __launch_bounds__(256) void rope_rms_kernel(
    float* __restrict__ qb, float* __restrict__ kb,
    const float* __restrict__ cosb, const float* __restrict__ sinb)
{
  int rid = blockIdx.x * 4 + (threadIdx.x >> 6);
  int lane = threadIdx.x & 63;
  float* p; int t;
  if (rid < TT * NH) { t = rid >> 4; p = qb + t * 1024 + (rid & 15) * 64; }
  else { int r2 = rid - TT * NH; t = r2 >> 3; p = kb + t * 512 + (r2 & 7) * 64; }

  float v = p[lane];
  float part = __shfl_xor(v, 32);
  int f = lane & 31;
  float c = cosb[t * 32 + f], s = sinb[t * 32 + f];
  float o = (lane < 32) ? (v * c - part * s) : (part * s + v * c);
  float ss = o * o;
#pragma unroll
  for (int off = 32; off; off >>= 1) ss += __shfl_xor(ss, off);
  float r = rsqrtf(ss * (1.0f / 64.0f) + EPS_);
  p[lane] = o * r;
}

// ---------------------------------------------------------------------------
// Transposes: kb[t][g*64+d] -> kt[g][d][t] (fp32);
//             vb[t][g*64+d] -> vt[g][d][t] (bf16).
// Grid 128: b<64 -> K, else V.
// ---------------------------------------------------------------------------
__global__ __launch_bounds__(256) void kvt_kernel(
    const float* __restrict__ kb, const float* __restrict__ vb,
    float* __restrict__ kt, ushort* __restrict__ vt)
{
  __shared__ float ft[64][65];
  int b = blockIdx.x;
  const bool isV = (b >= 64);
  if (isV) b -= 64;
  const int g = b >> 3, t0 = (b & 7) * 64;
  const float* src = isV ? vb : kb;
  const int tid = threadIdx.x;
  const int r16 = tid >> 4, c4 = tid & 15;
#pragma unroll
  for (int it = 0; it < 4; ++it) {
    int row = r16 + it * 16;
    float4 f = *reinterpret_cast<const float4*>(&src[(t0 + row) * 512 + g * 64 + c4 * 4]);
    ft[row][c4 * 4 + 0] = f.x; ft[row][c4 * 4 + 1] = f.y;
    ft[row][c4 * 4 + 2] = f.z; ft[row][c4 * 4 + 3] = f.w;
  }
  __syncthreads();
#pragma unroll
  for (int it = 0; it < 4; ++it) {
    int d = r16 + it * 16;
    if (isV) {
      uint2 o;
      o.x = (uint)f2bf(ft[c4 * 4 + 0][d]) | ((uint)f2bf(ft[c4 * 4 + 1][d]) << 16);
      o.y = (uint)f2bf(ft[c4 * 4 + 2][d]) | ((uint)f2bf(ft[c4 * 4 + 3][d]) << 16);
      *reinterpret_cast<uint2*>(&vt[g * 32768 + d * 512 + t0 + c4 * 4]) = o;
    } else {
      float4 o = make_float4(ft[c4 * 4 + 0][d], ft[c4 * 4 + 1][d],
                             ft[c4 * 4 + 2][d], ft[c4 * 4 + 3][d]);
      *reinterpret_cast<float4*>(&kt[g * 32768 + d * 512 + t0 + c4 * 4]) = o;
    }
  }
}

// ---------------------------------------------------------------------------
// Phase A: tropical scores + exp -> P (bf16), row-sums -> plsum (atomic).
// Zero LDS. Unit = one wave = (head h, 16 q-rows, one 64-j tile); 2304
// uniform units, 4 per block (576 blocks). K columns in regs from kt
// (coalesced, L2); q rows are wave-uniform loads; P store coalesced 128B.
// Deferred softmax: q,k RMS-normed => |s|<=16, exp safe, sums associative.
// ---------------------------------------------------------------------------
__global__ __launch_bounds__(256) void score_kernel(
    const float* __restrict__ qb, const float* __restrict__ kt,
    ushort* __restrict__ Pb, float* __restrict__ plsum)
{
  const int tid = threadIdx.x;
  const int w = tid >> 6, lane = tid & 63;
  const int u = blockIdx.x * 4 + w;      // 0..2303
  const int h = u / 144;
  const int r = u - h * 144;
  const int A = (r >= 4) + (r >= 12) + (r >= 24) + (r >= 40) +
                (r >= 60) + (r >= 84) + (r >= 112);
  const int rb = r - 2 * A * (A + 1);
  const int c = 4 * A + rb / (A + 1);
  const int jt = rb % (A + 1);
  const int g = h >> 1;
  const int i0 = c * 16;
  const int j0 = jt * 64;
  const bool diag = (jt == A);

  // K column block (lane = j) from kt, coalesced fp32
  float kreg[64];
  const float* ktp = &kt[g * 32768 + j0 + lane];
#pragma unroll
  for (int d = 0; d < 64; ++d) kreg[d] = ktp[d * 512];

  const float* qp = &qb[i0 * 1024 + h * 64];
  ushort* pp = &Pb[h * (TT * TT) + i0 * 512 + j0 + lane];

#pragma unroll 2
  for (int q = 0; q < 16; ++q) {
    float s0 = -INFINITY, s1 = -INFINITY;
#pragma unroll
    for (int d4 = 0; d4 < 16; ++d4) {
      float4 qv = *reinterpret_cast<const float4*>(qp + q * 1024 + d4 * 4);
      s0 = fmaxf(fmaxf(s0, qv.x + kreg[d4 * 4 + 0]), qv.y + kreg[d4 * 4 + 1]);
      s1 = fmaxf(fmaxf(s1, qv.z + kreg[d4 * 4 + 2]), qv.w + kreg[d4 * 4 + 3]);
    }
    float s = fmaxf(s0, s1);
    if (diag && (j0 + lane > i0 + q)) s = -INFINITY;
    float p = __expf(s);
    pp[q * 512] = f2bf(p);
    float l = p;
#pragma unroll
    for (int off = 32; off; off >>= 1) l += __shfl_xor(l, off);
    if (lane == 0) atomicAdd(&plsum[h * 512 + i0 + q], l);
  }
}

// ---------------------------------------------------------------------------
// Phase B: y = (P @ V) / l via bf16 MFMA. Block = (head h, 64-row i-chunk):
// 128 blocks, serial over causal j-tiles. Wave = 16 rows x all 64 d.
// A = P tile (row-major), B = V^T tile (n-major) — proven fragment paths.
// ---------------------------------------------------------------------------
__global__ __launch_bounds__(256) void pv_kernel(
    const ushort* __restrict__ Pb, const ushort* __restrict__ vt,
    const float* __restrict__ plsum, ushort* __restrict__ yb)
{
  __shared__ __align__(16) ushort Ps[64][68];
  __shared__ __align__(16) ushort Vs[64][68];
  const int tid = threadIdx.x;
  const int w = tid >> 6, lane = tid & 63;
  const int bx = blockIdx.x;
  const int h = bx & 15;
  const int cc = 7 - (bx >> 4);          // heavy chunks first
  const int g = h >> 1;
  const int i0 = cc * 64;
  const int rbw = w * 16;
  const int lr = lane & 15, lk = (lane >> 4) * 8;
  f32x4 acc[4] = {};

  const int srow = tid >> 2, scol = (tid & 3) * 16;
  for (int jt = 0; jt <= cc; ++jt) {
    const int j0 = jt * 64;
    __syncthreads();
    {
      const ushort* ps = &Pb[h * (TT * TT) + (i0 + srow) * 512 + j0 + scol];
      uint4 a0 = *reinterpret_cast<const uint4*>(ps);
      uint4 a1 = *reinterpret_cast<const uint4*>(ps + 8);
      const ushort* vs = &vt[g * 32768 + srow * 512 + j0 + scol];
      uint4 b0 = *reinterpret_cast<const uint4*>(vs);
      uint4 b1 = *reinterpret_cast<const uint4*>(vs + 8);
      *reinterpret_cast<uint4*>(&Ps[srow][scol]) = a0;
      *reinterpret_cast<uint4*>(&Ps[srow][scol + 8]) = a1;
      *reinterpret_cast<uint4*>(&Vs[srow][scol]) = b0;
      *reinterpret_cast<uint4*>(&Vs[srow][scol + 8]) = b1;
    }
    __syncthreads();
#pragma unroll
    for (int kk = 0; kk < 2; ++kk) {
      bf16x8 af = *reinterpret_cast<const bf16x8*>(&Ps[rbw + lr][kk * 32 + lk]);
#pragma unroll
      for (int ni = 0; ni < 4; ++ni) {
        bf16x8 bg = *reinterpret_cast<const bf16x8*>(&Vs[ni * 16 + lr][kk * 32 + lk]);
        acc[ni] = __builtin_amdgcn_mfma_f32_16x16x32_bf16(af, bg, acc[ni], 0, 0, 0);
      }
    }
  }

  const int crow = (lane >> 4) * 4, ccol = lane & 15;
#pragma unroll
  for (int r = 0; r < 4; ++r) {
    int i = i0 + rbw + crow + r;
    float linv = 1.0f / plsum[h * 512 + i];
#pragma unroll
    for (int ni = 0; ni < 4; ++ni)
      yb[i * 1024 + h * 64 + ni * 16 + ccol] = f2bf(acc[ni][r] * linv);
  }
}

// ---------------------------------------------------------------------------
extern "C" void kernel_launch(void* const* d_in, const int* in_sizes, int n_in,
                              void* d_out, int out_size, void* d_ws, size_t ws_size,
                              hipStream_t stream) {
  const float* x    = (const float*)d_in[0];
  const float* cosb = (const float*)d_in[1];
  const float* sinb = (const float*)d_in[2];
  const float* Wq   = (const float*)d_in[3];
  const float* Wk   = (const float*)d_in[4];
  const float* Wv   = (const float*)d_in[5];
  const float* Wo   = (const float*)d_in[6];
  float* out = (float*)d_out;

  float* wsf = (float*)d_ws;
  float* qbuf  = wsf;                      // 512x1024 f32
  float* kbuf  = qbuf + TT * CC;           // 512x512  f32
  float* vbuf  = kbuf + TT * 512;          // 512x512  f32
  float* ktb   = vbuf + TT * 512;          // 8x64x512 f32 (K^T per kv head)
  float* plsum = ktb + 8 * 64 * 512;       // 16x512 f32 row sums (atomic)
  ushort* wsu = (ushort*)(plsum + NH * TT);
  ushort* xb  = wsu;                       // 512x1024 bf16
  ushort* yb  = xb + TT * CC;              // 512x1024 bf16
  ushort* Pb  = yb + TT * CC;              // 16x512x512 bf16 (P matrix)
  ushort* vtb = Pb + NH * TT * TT;         // 8x64x512 bf16 (V^T per kv head)
  ushort* Wtq = vtb + 8 * 64 * 512;        // 1024x1024 bf16
  ushort* Wtk = Wtq + CC * CC;             // 512x1024 bf16
  ushort* Wtv = Wtk + 512 * CC;            // 512x1024 bf16
  ushort* Wto = Wtv + 512 * CC;            // 1024x1024 bf16

  hipMemsetAsync(plsum, 0, NH * TT * sizeof(float), stream);
  prep_kernel<<<dim3(1024), 256, 0, stream>>>(x, Wq, Wk, Wv, Wo, xb, Wtq, Wtk, Wtv, Wto);
  qkv_mfma_kernel<<<dim3(32, 8), 256, 0, stream>>>(xb, Wtq, Wtk, Wtv, qbuf, kbuf, vbuf);
  rope_rms_kernel<<<dim3((TT * NH + TT * NKV) / 4), 256, 0, stream>>>(qbuf, kbuf, cosb, sinb);
  kvt_kernel<<<dim3(128), 256, 0, stream>>>(kbuf, vbuf, ktb, vtb);
  score_kernel<<<dim3(576), 256, 0, stream>>>(qbuf, ktb, Pb, plsum);
  pv_kernel<<<dim3(128), 256, 0, stream>>>(Pb, vtb, plsum, yb);
  out_mfma_kernel<<<dim3(16, 8), 256, 0, stream>>>(yb, Wto, out);
}

// Round 10
// 75.844 us; speedup vs baseline: 1.9617x; 1.1311x over previous
//
#include <hip/hip_runtime.h>
#include <hip/hip_bf16.h>
#include <math.h>

#define TT 512
#define CC 1024
#define NH 16
#define NKV 8
#define HD 64
static constexpr float EPS_ = 1e-6f;

typedef short bf16x8 __attribute__((ext_vector_type(8)));
typedef float f32x4 __attribute__((ext_vector_type(4)));

__device__ __forceinline__ ushort f2bf(float f) {
  union { __hip_bfloat16 h; ushort u; } cv;
  cv.h = __float2bfloat16(f);
  return cv.u;
}

__device__ __forceinline__ void gload16(const ushort* g, ushort* l) {
  __builtin_amdgcn_global_load_lds(
      (const __attribute__((address_space(1))) unsigned int*)g,
      (__attribute__((address_space(3))) unsigned int*)l, 16, 0, 0);
}

// ---------------------------------------------------------------------------
// prep: x -> bf16 (same layout); Wq/Wk/Wv/Wo -> transposed bf16 Wt[n][k]
// ---------------------------------------------------------------------------
__global__ __launch_bounds__(256) void prep_kernel(
    const float* __restrict__ x,
    const float* __restrict__ Wq, const float* __restrict__ Wk,
    const float* __restrict__ Wv, const float* __restrict__ Wo,
    ushort* __restrict__ xb, ushort* __restrict__ Wtq, ushort* __restrict__ Wtk,
    ushort* __restrict__ Wtv, ushort* __restrict__ Wto)
{
  int b = blockIdx.x;
  if (b < 256) {
    int base = b * 2048 + threadIdx.x * 8;
    float4 f0 = *reinterpret_cast<const float4*>(&x[base]);
    float4 f1 = *reinterpret_cast<const float4*>(&x[base + 4]);
    union { ushort u[8]; uint4 v; } pk;
    pk.u[0] = f2bf(f0.x); pk.u[1] = f2bf(f0.y); pk.u[2] = f2bf(f0.z); pk.u[3] = f2bf(f0.w);
    pk.u[4] = f2bf(f1.x); pk.u[5] = f2bf(f1.y); pk.u[6] = f2bf(f1.z); pk.u[7] = f2bf(f1.w);
    *reinterpret_cast<uint4*>(&xb[base]) = pk.v;
    return;
  }
  b -= 256;
  const float* W; ushort* Wt; int ldW, tr, tc;
  if (b < 256)      { W = Wq; Wt = Wtq; ldW = 1024; tr = b >> 4;       tc = b & 15; }
  else if (b < 384) { int q = b - 256; W = Wk; Wt = Wtk; ldW = 512; tr = q >> 3; tc = q & 7; }
  else if (b < 512) { int q = b - 384; W = Wv; Wt = Wtv; ldW = 512; tr = q >> 3; tc = q & 7; }
  else              { int q = b - 512; W = Wo; Wt = Wto; ldW = 1024; tr = q >> 4; tc = q & 15; }
  const int k0 = tr * 64, n0 = tc * 64;
  __shared__ float ft[64][65];
  const int t = threadIdx.x;
#pragma unroll
  for (int it = 0; it < 4; ++it) {
    int q = t + it * 256;
    int r = q >> 4, c4 = q & 15;
    float4 f = *reinterpret_cast<const float4*>(&W[(k0 + r) * ldW + n0 + c4 * 4]);
    ft[r][c4 * 4 + 0] = f.x; ft[r][c4 * 4 + 1] = f.y;
    ft[r][c4 * 4 + 2] = f.z; ft[r][c4 * 4 + 3] = f.w;
  }
  __syncthreads();
#pragma unroll
  for (int it = 0; it < 2; ++it) {
    int q = t + it * 256;
    int n = q >> 3, kc = q & 7;
    union { ushort u[8]; uint4 v; } pk;
#pragma unroll
    for (int j = 0; j < 8; ++j) pk.u[j] = f2bf(ft[kc * 8 + j][n]);
    *reinterpret_cast<uint4*>(&Wt[(n0 + n) * 1024 + k0 + kc * 8]) = pk.v;
  }
}

// ---------------------------------------------------------------------------
// bf16 MFMA GEMM: C[64x64 tile] = A[M][1024] @ Bt[N][1024]^T, fp32 out.
// ---------------------------------------------------------------------------
__device__ __forceinline__ void mfma_gemm64(
    const ushort* __restrict__ A, const ushort* __restrict__ Bt,
    float* __restrict__ C, int ldC, int row0, int col0)
{
  __shared__ __align__(16) ushort At[64 * 64];
  __shared__ __align__(16) ushort Bs[64 * 64];
  const int tid = threadIdx.x;
  const int lane = tid & 63, w = tid >> 6;
  const int m0 = (w & 1) * 32, n0 = (w >> 1) * 32;
  const int lr = lane & 15, lk = (lane >> 4) * 8;
  f32x4 acc[2][2] = {};
  const int srow = tid >> 3, sc8 = (tid & 7) * 8;
  const ushort* Ap = &A[(row0 + srow) * 1024 + sc8];
  const ushort* Bp = &Bt[(col0 + srow) * 1024 + sc8];
  ushort* Al = &At[tid * 8];
  ushort* Bl = &Bs[tid * 8];

  for (int k0 = 0; k0 < 1024; k0 += 64) {
    __syncthreads();
    gload16(Ap + k0, Al);
    gload16(Ap + 32 * 1024 + k0, Al + 2048);
    gload16(Bp + k0, Bl);
    gload16(Bp + 32 * 1024 + k0, Bl + 2048);
    __syncthreads();
#pragma unroll
    for (int kk = 0; kk < 2; ++kk) {
      bf16x8 af[2], bg[2];
      af[0] = *reinterpret_cast<const bf16x8*>(&At[(m0 + lr) * 64 + kk * 32 + lk]);
      af[1] = *reinterpret_cast<const bf16x8*>(&At[(m0 + 16 + lr) * 64 + kk * 32 + lk]);
      bg[0] = *reinterpret_cast<const bf16x8*>(&Bs[(n0 + lr) * 64 + kk * 32 + lk]);
      bg[1] = *reinterpret_cast<const bf16x8*>(&Bs[(n0 + 16 + lr) * 64 + kk * 32 + lk]);
#pragma unroll
      for (int mi = 0; mi < 2; ++mi)
#pragma unroll
        for (int ni = 0; ni < 2; ++ni)
          acc[mi][ni] = __builtin_amdgcn_mfma_f32_16x16x32_bf16(af[mi], bg[ni], acc[mi][ni], 0, 0, 0);
    }
  }
  const int crow = (lane >> 4) * 4, ccol = lane & 15;
#pragma unroll
  for (int mi = 0; mi < 2; ++mi)
#pragma unroll
    for (int ni = 0; ni < 2; ++ni) {
      int rb = row0 + m0 + mi * 16 + crow;
      int cc = col0 + n0 + ni * 16 + ccol;
#pragma unroll
      for (int r = 0; r < 4; ++r)
        C[(rb + r) * ldC + cc] = acc[mi][ni][r];
    }
}

__global__ __launch_bounds__(256) void qkv_mfma_kernel(
    const ushort* __restrict__ xb,
    const ushort* __restrict__ Wtq, const ushort* __restrict__ Wtk, const ushort* __restrict__ Wtv,
    float* __restrict__ qb, float* __restrict__ kb, float* __restrict__ vb)
{
  int bx = blockIdx.x, by = blockIdx.y;
  if (bx < 16)      mfma_gemm64(xb, Wtq, qb, 1024, by * 64, bx * 64);
  else if (bx < 24) mfma_gemm64(xb, Wtk, kb, 512, by * 64, (bx - 16) * 64);
  else              mfma_gemm64(xb, Wtv, vb, 512, by * 64, (bx - 24) * 64);
}

__global__ __launch_bounds__(256) void out_mfma_kernel(
    const ushort* __restrict__ yb, const ushort* __restrict__ Wto, float* __restrict__ out)
{
  mfma_gemm64(yb, Wto, out, 1024, blockIdx.y * 64, blockIdx.x * 64);
}

// ---------------------------------------------------------------------------
// RoPE + RMS-norm, in place (fp32).
// ---------------------------------------------------------------------------
__global__ __launch_bounds__(256) void rope_rms_kernel(
    float* __restrict__ qb, float* __restrict__ kb,
    const float* __restrict__ cosb, const float* __restrict__ sinb)
{
  int rid = blockIdx.x * 4 + (threadIdx.x >> 6);
  int lane = threadIdx.x & 63;
  float* p; int t;
  if (rid < TT * NH) { t = rid >> 4; p = qb + t * 1024 + (rid & 15) * 64; }
  else { int r2 = rid - TT * NH; t = r2 >> 3; p = kb + t * 512 + (r2 & 7) * 64; }

  float v = p[lane];
  float part = __shfl_xor(v, 32);
  int f = lane & 31;
  float c = cosb[t * 32 + f], s = sinb[t * 32 + f];
  float o = (lane < 32) ? (v * c - part * s) : (part * s + v * c);
  float ss = o * o;
#pragma unroll
  for (int off = 32; off; off >>= 1) ss += __shfl_xor(ss, off);
  float r = rsqrtf(ss * (1.0f / 64.0f) + EPS_);
  p[lane] = o * r;
}

// ---------------------------------------------------------------------------
// Transposes: kb[t][g*64+d] -> kt[g][d][t] (fp32);
//             vb[t][g*64+d] -> vt[g][d][t] (bf16).
// Grid 128: b<64 -> K, else V.
// ---------------------------------------------------------------------------
__global__ __launch_bounds__(256) void kvt_kernel(
    const float* __restrict__ kb, const float* __restrict__ vb,
    float* __restrict__ kt, ushort* __restrict__ vt)
{
  __shared__ float ft[64][65];
  int b = blockIdx.x;
  const bool isV = (b >= 64);
  if (isV) b -= 64;
  const int g = b >> 3, t0 = (b & 7) * 64;
  const float* src = isV ? vb : kb;
  const int tid = threadIdx.x;
  const int r16 = tid >> 4, c4 = tid & 15;
#pragma unroll
  for (int it = 0; it < 4; ++it) {
    int row = r16 + it * 16;
    float4 f = *reinterpret_cast<const float4*>(&src[(t0 + row) * 512 + g * 64 + c4 * 4]);
    ft[row][c4 * 4 + 0] = f.x; ft[row][c4 * 4 + 1] = f.y;
    ft[row][c4 * 4 + 2] = f.z; ft[row][c4 * 4 + 3] = f.w;
  }
  __syncthreads();
#pragma unroll
  for (int it = 0; it < 4; ++it) {
    int d = r16 + it * 16;
    if (isV) {
      uint2 o;
      o.x = (uint)f2bf(ft[c4 * 4 + 0][d]) | ((uint)f2bf(ft[c4 * 4 + 1][d]) << 16);
      o.y = (uint)f2bf(ft[c4 * 4 + 2][d]) | ((uint)f2bf(ft[c4 * 4 + 3][d]) << 16);
      *reinterpret_cast<uint2*>(&vt[g * 32768 + d * 512 + t0 + c4 * 4]) = o;
    } else {
      float4 o = make_float4(ft[c4 * 4 + 0][d], ft[c4 * 4 + 1][d],
                             ft[c4 * 4 + 2][d], ft[c4 * 4 + 3][d]);
      *reinterpret_cast<float4*>(&kt[g * 32768 + d * 512 + t0 + c4 * 4]) = o;
    }
  }
}

// ---------------------------------------------------------------------------
// Phase A: tropical scores + exp -> P (bf16). Zero LDS, zero reductions.
// Unit = one wave = (head h, 16 q-rows, one 64-j tile); 2304 uniform units,
// 4 per block (576 blocks). K columns in regs from kt (coalesced, L2);
// q rows wave-uniform loads; P store coalesced 128B.
// Deferred softmax: q,k RMS-normed => |s|<=16, exp safe; denominators are
// computed in pv_kernel via ones-MFMA.
// ---------------------------------------------------------------------------
__global__ __launch_bounds__(256) void score_kernel(
    const float* __restrict__ qb, const float* __restrict__ kt,
    ushort* __restrict__ Pb)
{
  const int tid = threadIdx.x;
  const int w = tid >> 6, lane = tid & 63;
  const int u = blockIdx.x * 4 + w;      // 0..2303
  const int h = u / 144;
  const int r = u - h * 144;
  const int A = (r >= 4) + (r >= 12) + (r >= 24) + (r >= 40) +
                (r >= 60) + (r >= 84) + (r >= 112);
  const int rb = r - 2 * A * (A + 1);
  const int c = 4 * A + rb / (A + 1);
  const int jt = rb % (A + 1);
  const int g = h >> 1;
  const int i0 = c * 16;
  const int j0 = jt * 64;
  const bool diag = (jt == A);

  // K column block (lane = j) from kt, coalesced fp32
  float kreg[64];
  const float* ktp = &kt[g * 32768 + j0 + lane];
#pragma unroll
  for (int d = 0; d < 64; ++d) kreg[d] = ktp[d * 512];

  const float* qp = &qb[i0 * 1024 + h * 64];
  ushort* pp = &Pb[h * (TT * TT) + i0 * 512 + j0 + lane];

#pragma unroll 2
  for (int q = 0; q < 16; ++q) {
    float s0 = -INFINITY, s1 = -INFINITY;
#pragma unroll
    for (int d4 = 0; d4 < 16; ++d4) {
      float4 qv = *reinterpret_cast<const float4*>(qp + q * 1024 + d4 * 4);
      s0 = fmaxf(fmaxf(s0, qv.x + kreg[d4 * 4 + 0]), qv.y + kreg[d4 * 4 + 1]);
      s1 = fmaxf(fmaxf(s1, qv.z + kreg[d4 * 4 + 2]), qv.w + kreg[d4 * 4 + 3]);
    }
    float s = fmaxf(s0, s1);
    if (diag && (j0 + lane > i0 + q)) s = -INFINITY;
    pp[q * 512] = f2bf(__expf(s));       // masked lanes: exp(-inf)=0
  }
}

// ---------------------------------------------------------------------------
// Phase B: y = (P @ V) / rowsum(P) via bf16 MFMA. Block = (head h, 64-row
// i-chunk): 128 blocks, serial over causal j-tiles; heavy chunks first.
// Row sums come free from an extra MFMA with an all-ones B fragment.
// ---------------------------------------------------------------------------
__global__ __launch_bounds__(256) void pv_kernel(
    const ushort* __restrict__ Pb, const ushort* __restrict__ vt,
    ushort* __restrict__ yb)
{
  __shared__ __align__(16) ushort Ps[64][68];
  __shared__ __align__(16) ushort Vs[64][68];
  const int tid = threadIdx.x;
  const int w = tid >> 6, lane = tid & 63;
  const int bx = blockIdx.x;
  const int h = bx & 15;
  const int cc = 7 - (bx >> 4);          // heavy chunks first
  const int g = h >> 1;
  const int i0 = cc * 64;
  const int rbw = w * 16;
  const int lr = lane & 15, lk = (lane >> 4) * 8;
  f32x4 acc[4] = {};
  f32x4 accl = {};                       // row sums via ones-MFMA

  bf16x8 ones;
#pragma unroll
  for (int e = 0; e < 8; ++e) ones[e] = (short)0x3F80;   // bf16 1.0

  const int srow = tid >> 2, scol = (tid & 3) * 16;
  for (int jt = 0; jt <= cc; ++jt) {
    const int j0 = jt * 64;
    __syncthreads();
    {
      const ushort* ps = &Pb[h * (TT * TT) + (i0 + srow) * 512 + j0 + scol];
      uint4 a0 = *reinterpret_cast<const uint4*>(ps);
      uint4 a1 = *reinterpret_cast<const uint4*>(ps + 8);
      const ushort* vs = &vt[g * 32768 + srow * 512 + j0 + scol];
      uint4 b0 = *reinterpret_cast<const uint4*>(vs);
      uint4 b1 = *reinterpret_cast<const uint4*>(vs + 8);
      *reinterpret_cast<uint4*>(&Ps[srow][scol]) = a0;
      *reinterpret_cast<uint4*>(&Ps[srow][scol + 8]) = a1;
      *reinterpret_cast<uint4*>(&Vs[srow][scol]) = b0;
      *reinterpret_cast<uint4*>(&Vs[srow][scol + 8]) = b1;
    }
    __syncthreads();
#pragma unroll
    for (int kk = 0; kk < 2; ++kk) {
      bf16x8 af = *reinterpret_cast<const bf16x8*>(&Ps[rbw + lr][kk * 32 + lk]);
      accl = __builtin_amdgcn_mfma_f32_16x16x32_bf16(af, ones, accl, 0, 0, 0);
#pragma unroll
      for (int ni = 0; ni < 4; ++ni) {
        bf16x8 bg = *reinterpret_cast<const bf16x8*>(&Vs[ni * 16 + lr][kk * 32 + lk]);
        acc[ni] = __builtin_amdgcn_mfma_f32_16x16x32_bf16(af, bg, acc[ni], 0, 0, 0);
      }
    }
  }

  const int crow = (lane >> 4) * 4, ccol = lane & 15;
#pragma unroll
  for (int r = 0; r < 4; ++r) {
    int i = i0 + rbw + crow + r;
    float linv = 1.0f / accl[r];         // same across cols
#pragma unroll
    for (int ni = 0; ni < 4; ++ni)
      yb[i * 1024 + h * 64 + ni * 16 + ccol] = f2bf(acc[ni][r] * linv);
  }
}

// ---------------------------------------------------------------------------
extern "C" void kernel_launch(void* const* d_in, const int* in_sizes, int n_in,
                              void* d_out, int out_size, void* d_ws, size_t ws_size,
                              hipStream_t stream) {
  const float* x    = (const float*)d_in[0];
  const float* cosb = (const float*)d_in[1];
  const float* sinb = (const float*)d_in[2];
  const float* Wq   = (const float*)d_in[3];
  const float* Wk   = (const float*)d_in[4];
  const float* Wv   = (const float*)d_in[5];
  const float* Wo   = (const float*)d_in[6];
  float* out = (float*)d_out;

  float* wsf = (float*)d_ws;
  float* qbuf  = wsf;                      // 512x1024 f32
  float* kbuf  = qbuf + TT * CC;           // 512x512  f32
  float* vbuf  = kbuf + TT * 512;          // 512x512  f32
  float* ktb   = vbuf + TT * 512;          // 8x64x512 f32 (K^T per kv head)
  ushort* wsu = (ushort*)(ktb + 8 * 64 * 512);
  ushort* xb  = wsu;                       // 512x1024 bf16
  ushort* yb  = xb + TT * CC;              // 512x1024 bf16
  ushort* Pb  = yb + TT * CC;              // 16x512x512 bf16 (P matrix)
  ushort* vtb = Pb + NH * TT * TT;         // 8x64x512 bf16 (V^T per kv head)
  ushort* Wtq = vtb + 8 * 64 * 512;        // 1024x1024 bf16
  ushort* Wtk = Wtq + CC * CC;             // 512x1024 bf16
  ushort* Wtv = Wtk + 512 * CC;            // 512x1024 bf16
  ushort* Wto = Wtv + 512 * CC;            // 1024x1024 bf16

  prep_kernel<<<dim3(1024), 256, 0, stream>>>(x, Wq, Wk, Wv, Wo, xb, Wtq, Wtk, Wtv, Wto);
  qkv_mfma_kernel<<<dim3(32, 8), 256, 0, stream>>>(xb, Wtq, Wtk, Wtv, qbuf, kbuf, vbuf);
  rope_rms_kernel<<<dim3((TT * NH + TT * NKV) / 4), 256, 0, stream>>>(qbuf, kbuf, cosb, sinb);
  kvt_kernel<<<dim3(128), 256, 0, stream>>>(kbuf, vbuf, ktb, vtb);
  score_kernel<<<dim3(576), 256, 0, stream>>>(qbuf, ktb, Pb);
  pv_kernel<<<dim3(128), 256, 0, stream>>>(Pb, vtb, yb);
  out_mfma_kernel<<<dim3(16, 8), 256, 0, stream>>>(yb, Wto, out);
}

// Round 11
// 75.015 us; speedup vs baseline: 1.9834x; 1.0111x over previous
//
#include <hip/hip_runtime.h>
#include <hip/hip_bf16.h>
#include <math.h>

#define TT 512
#define CC 1024
#define NH 16
#define NKV 8
#define HD 64
static constexpr float EPS_ = 1e-6f;

typedef short bf16x8 __attribute__((ext_vector_type(8)));
typedef float f32x4 __attribute__((ext_vector_type(4)));

__device__ __forceinline__ ushort f2bf(float f) {
  union { __hip_bfloat16 h; ushort u; } cv;
  cv.h = __float2bfloat16(f);
  return cv.u;
}

// ---------------------------------------------------------------------------
// prep: x -> bf16 (same layout); Wq/Wk/Wv/Wo -> transposed bf16 Wt[n][k]
// ---------------------------------------------------------------------------
__global__ __launch_bounds__(256) void prep_kernel(
    const float* __restrict__ x,
    const float* __restrict__ Wq, const float* __restrict__ Wk,
    const float* __restrict__ Wv, const float* __restrict__ Wo,
    ushort* __restrict__ xb, ushort* __restrict__ Wtq, ushort* __restrict__ Wtk,
    ushort* __restrict__ Wtv, ushort* __restrict__ Wto)
{
  int b = blockIdx.x;
  if (b < 256) {
    int base = b * 2048 + threadIdx.x * 8;
    float4 f0 = *reinterpret_cast<const float4*>(&x[base]);
    float4 f1 = *reinterpret_cast<const float4*>(&x[base + 4]);
    union { ushort u[8]; uint4 v; } pk;
    pk.u[0] = f2bf(f0.x); pk.u[1] = f2bf(f0.y); pk.u[2] = f2bf(f0.z); pk.u[3] = f2bf(f0.w);
    pk.u[4] = f2bf(f1.x); pk.u[5] = f2bf(f1.y); pk.u[6] = f2bf(f1.z); pk.u[7] = f2bf(f1.w);
    *reinterpret_cast<uint4*>(&xb[base]) = pk.v;
    return;
  }
  b -= 256;
  const float* W; ushort* Wt; int ldW, tr, tc;
  if (b < 256)      { W = Wq; Wt = Wtq; ldW = 1024; tr = b >> 4;       tc = b & 15; }
  else if (b < 384) { int q = b - 256; W = Wk; Wt = Wtk; ldW = 512; tr = q >> 3; tc = q & 7; }
  else if (b < 512) { int q = b - 384; W = Wv; Wt = Wtv; ldW = 512; tr = q >> 3; tc = q & 7; }
  else              { int q = b - 512; W = Wo; Wt = Wto; ldW = 1024; tr = q >> 4; tc = q & 15; }
  const int k0 = tr * 64, n0 = tc * 64;
  __shared__ float ft[64][65];
  const int t = threadIdx.x;
#pragma unroll
  for (int it = 0; it < 4; ++it) {
    int q = t + it * 256;
    int r = q >> 4, c4 = q & 15;
    float4 f = *reinterpret_cast<const float4*>(&W[(k0 + r) * ldW + n0 + c4 * 4]);
    ft[r][c4 * 4 + 0] = f.x; ft[r][c4 * 4 + 1] = f.y;
    ft[r][c4 * 4 + 2] = f.z; ft[r][c4 * 4 + 3] = f.w;
  }
  __syncthreads();
#pragma unroll
  for (int it = 0; it < 2; ++it) {
    int q = t + it * 256;
    int n = q >> 3, kc = q & 7;
    union { ushort u[8]; uint4 v; } pk;
#pragma unroll
    for (int j = 0; j < 8; ++j) pk.u[j] = f2bf(ft[kc * 8 + j][n]);
    *reinterpret_cast<uint4*>(&Wt[(n0 + n) * 1024 + k0 + kc * 8]) = pk.v;
  }
}

// ---------------------------------------------------------------------------
// bf16 MFMA GEMM (R2-proven): C[64x64] = A[M][1024] @ Bt[N][1024]^T, fp32 out.
// Padded LDS [64][72]: fragment ds_read_b128 row stride 144B -> <=2-way
// conflicts (free). Explicit register staging.
// ---------------------------------------------------------------------------
__device__ __forceinline__ void mfma_gemm64(
    const ushort* __restrict__ A, const ushort* __restrict__ Bt,
    float* __restrict__ C, int ldC, int row0, int col0)
{
  __shared__ ushort At[64][72];
  __shared__ ushort Bs[64][72];
  const int tid = threadIdx.x;
  const int lane = tid & 63, w = tid >> 6;
  const int m0 = (w & 1) * 32, n0 = (w >> 1) * 32;
  const int lr = lane & 15, lk = (lane >> 4) * 8;
  f32x4 acc[2][2] = {};
  const int sr = tid >> 2;
  const int sc = (tid & 3) * 16;
  const ushort* Ap = &A[(row0 + sr) * 1024 + sc];
  const ushort* Bp = &Bt[(col0 + sr) * 1024 + sc];

  for (int k0 = 0; k0 < 1024; k0 += 64) {
    __syncthreads();
    uint4 a0 = *reinterpret_cast<const uint4*>(Ap + k0);
    uint4 a1 = *reinterpret_cast<const uint4*>(Ap + k0 + 8);
    uint4 b0 = *reinterpret_cast<const uint4*>(Bp + k0);
    uint4 b1 = *reinterpret_cast<const uint4*>(Bp + k0 + 8);
    *reinterpret_cast<uint4*>(&At[sr][sc]) = a0;
    *reinterpret_cast<uint4*>(&At[sr][sc + 8]) = a1;
    *reinterpret_cast<uint4*>(&Bs[sr][sc]) = b0;
    *reinterpret_cast<uint4*>(&Bs[sr][sc + 8]) = b1;
    __syncthreads();
#pragma unroll
    for (int kk = 0; kk < 2; ++kk) {
      bf16x8 af[2], bg[2];
      af[0] = *reinterpret_cast<const bf16x8*>(&At[m0 + lr][kk * 32 + lk]);
      af[1] = *reinterpret_cast<const bf16x8*>(&At[m0 + 16 + lr][kk * 32 + lk]);
      bg[0] = *reinterpret_cast<const bf16x8*>(&Bs[n0 + lr][kk * 32 + lk]);
      bg[1] = *reinterpret_cast<const bf16x8*>(&Bs[n0 + 16 + lr][kk * 32 + lk]);
#pragma unroll
      for (int mi = 0; mi < 2; ++mi)
#pragma unroll
        for (int ni = 0; ni < 2; ++ni)
          acc[mi][ni] = __builtin_amdgcn_mfma_f32_16x16x32_bf16(af[mi], bg[ni], acc[mi][ni], 0, 0, 0);
    }
  }
  const int crow = (lane >> 4) * 4, ccol = lane & 15;
#pragma unroll
  for (int mi = 0; mi < 2; ++mi)
#pragma unroll
    for (int ni = 0; ni < 2; ++ni) {
      int rb = row0 + m0 + mi * 16 + crow;
      int cc = col0 + n0 + ni * 16 + ccol;
#pragma unroll
      for (int r = 0; r < 4; ++r)
        C[(rb + r) * ldC + cc] = acc[mi][ni][r];
    }
}

__global__ __launch_bounds__(256) void qkv_mfma_kernel(
    const ushort* __restrict__ xb,
    const ushort* __restrict__ Wtq, const ushort* __restrict__ Wtk, const ushort* __restrict__ Wtv,
    float* __restrict__ qb, float* __restrict__ kb, float* __restrict__ vb)
{
  int bx = blockIdx.x, by = blockIdx.y;
  if (bx < 16)      mfma_gemm64(xb, Wtq, qb, 1024, by * 64, bx * 64);
  else if (bx < 24) mfma_gemm64(xb, Wtk, kb, 512, by * 64, (bx - 16) * 64);
  else              mfma_gemm64(xb, Wtv, vb, 512, by * 64, (bx - 24) * 64);
}

__global__ __launch_bounds__(256) void out_mfma_kernel(
    const ushort* __restrict__ yb, const ushort* __restrict__ Wto, float* __restrict__ out)
{
  mfma_gemm64(yb, Wto, out, 1024, blockIdx.y * 64, blockIdx.x * 64);
}

// ---------------------------------------------------------------------------
// Fused RoPE/RMS + transposes.
// Blocks [0,2048): q rows, rope+rms in place (4 rows x 4 waves).
// Blocks [2048,2112): K: rope+rms 64 rows of kv-head g, transpose -> kt[g][d][t]
//   (fp32), self-contained per block (no normalized-k round trip).
// Blocks [2112,2176): V: transpose vb tile -> vt[g][d][t] (bf16).
// ---------------------------------------------------------------------------
__global__ __launch_bounds__(256) void rope_fused_kernel(
    float* __restrict__ qb, const float* __restrict__ kb,
    const float* __restrict__ vb,
    const float* __restrict__ cosb, const float* __restrict__ sinb,
    float* __restrict__ kt, ushort* __restrict__ vt)
{
  const int b = blockIdx.x;
  const int tid = threadIdx.x;
  const int w = tid >> 6, lane = tid & 63;

  if (b < 2048) {                        // ---- q rope+rms, in place
    int rid = b * 4 + w;
    int t = rid >> 4;
    float* p = qb + t * 1024 + (rid & 15) * 64;
    float v = p[lane];
    float part = __shfl_xor(v, 32);
    int f = lane & 31;
    float c = cosb[t * 32 + f], s = sinb[t * 32 + f];
    float o = (lane < 32) ? (v * c - part * s) : (part * s + v * c);
    float ss = o * o;
#pragma unroll
    for (int off = 32; off; off >>= 1) ss += __shfl_xor(ss, off);
    float r = rsqrtf(ss * (1.0f / 64.0f) + EPS_);
    p[lane] = o * r;
    return;
  }

  __shared__ float ft[64][65];
  const int r16 = tid >> 4, c4 = tid & 15;

  if (b < 2112) {                        // ---- K: rope+rms + transpose -> kt
    const int idx = b - 2048;
    const int g = idx >> 3, t0 = (idx & 7) * 64;
    // each wave normalizes 16 rows (lane = d)
#pragma unroll 4
    for (int r = 0; r < 16; ++r) {
      int row = w * 16 + r;
      int t = t0 + row;
      float v = kb[t * 512 + g * 64 + lane];
      float part = __shfl_xor(v, 32);
      int f = lane & 31;
      float c = cosb[t * 32 + f], s = sinb[t * 32 + f];
      float o = (lane < 32) ? (v * c - part * s) : (part * s + v * c);
      float ss = o * o;
#pragma unroll
      for (int off = 32; off; off >>= 1) ss += __shfl_xor(ss, off);
      ft[row][lane] = o * rsqrtf(ss * (1.0f / 64.0f) + EPS_);
    }
    __syncthreads();
#pragma unroll
    for (int it = 0; it < 4; ++it) {
      int d = r16 + it * 16;
      float4 o = make_float4(ft[c4 * 4 + 0][d], ft[c4 * 4 + 1][d],
                             ft[c4 * 4 + 2][d], ft[c4 * 4 + 3][d]);
      *reinterpret_cast<float4*>(&kt[g * 32768 + d * 512 + t0 + c4 * 4]) = o;
    }
    return;
  }

  // ---- V: transpose -> vt (bf16)
  const int idx = b - 2112;
  const int g = idx >> 3, t0 = (idx & 7) * 64;
#pragma unroll
  for (int it = 0; it < 4; ++it) {
    int row = r16 + it * 16;
    float4 f = *reinterpret_cast<const float4*>(&vb[(t0 + row) * 512 + g * 64 + c4 * 4]);
    ft[row][c4 * 4 + 0] = f.x; ft[row][c4 * 4 + 1] = f.y;
    ft[row][c4 * 4 + 2] = f.z; ft[row][c4 * 4 + 3] = f.w;
  }
  __syncthreads();
#pragma unroll
  for (int it = 0; it < 4; ++it) {
    int d = r16 + it * 16;
    uint2 o;
    o.x = (uint)f2bf(ft[c4 * 4 + 0][d]) | ((uint)f2bf(ft[c4 * 4 + 1][d]) << 16);
    o.y = (uint)f2bf(ft[c4 * 4 + 2][d]) | ((uint)f2bf(ft[c4 * 4 + 3][d]) << 16);
    *reinterpret_cast<uint2*>(&vt[g * 32768 + d * 512 + t0 + c4 * 4]) = o;
  }
}

// ---------------------------------------------------------------------------
// Phase A: tropical scores + exp -> P (bf16). Zero LDS, zero reductions.
// Unit = one wave = (head h, 16 q-rows, one 64-j tile); 2304 uniform units.
// Deferred softmax: q,k RMS-normed => |s|<=16, exp safe; denominators via
// ones-MFMA in pv_kernel.
// ---------------------------------------------------------------------------
__global__ __launch_bounds__(256) void score_kernel(
    const float* __restrict__ qb, const float* __restrict__ kt,
    ushort* __restrict__ Pb)
{
  const int tid = threadIdx.x;
  const int w = tid >> 6, lane = tid & 63;
  const int u = blockIdx.x * 4 + w;      // 0..2303
  const int h = u / 144;
  const int r = u - h * 144;
  const int A = (r >= 4) + (r >= 12) + (r >= 24) + (r >= 40) +
                (r >= 60) + (r >= 84) + (r >= 112);
  const int rb = r - 2 * A * (A + 1);
  const int c = 4 * A + rb / (A + 1);
  const int jt = rb % (A + 1);
  const int g = h >> 1;
  const int i0 = c * 16;
  const int j0 = jt * 64;
  const bool diag = (jt == A);

  float kreg[64];
  const float* ktp = &kt[g * 32768 + j0 + lane];
#pragma unroll
  for (int d = 0; d < 64; ++d) kreg[d] = ktp[d * 512];

  const float* qp = &qb[i0 * 1024 + h * 64];
  ushort* pp = &Pb[h * (TT * TT) + i0 * 512 + j0 + lane];

#pragma unroll 2
  for (int q = 0; q < 16; ++q) {
    float s0 = -INFINITY, s1 = -INFINITY;
#pragma unroll
    for (int d4 = 0; d4 < 16; ++d4) {
      float4 qv = *reinterpret_cast<const float4*>(qp + q * 1024 + d4 * 4);
      s0 = fmaxf(fmaxf(s0, qv.x + kreg[d4 * 4 + 0]), qv.y + kreg[d4 * 4 + 1]);
      s1 = fmaxf(fmaxf(s1, qv.z + kreg[d4 * 4 + 2]), qv.w + kreg[d4 * 4 + 3]);
    }
    float s = fmaxf(s0, s1);
    if (diag && (j0 + lane > i0 + q)) s = -INFINITY;
    pp[q * 512] = f2bf(__expf(s));       // masked lanes: exp(-inf)=0
  }
}

// ---------------------------------------------------------------------------
// Phase B: y = (P @ V) / rowsum(P) via bf16 MFMA; rowsum free via ones-MFMA.
// Block = (head h, 64-row i-chunk); heavy chunks first.
// ---------------------------------------------------------------------------
__global__ __launch_bounds__(256) void pv_kernel(
    const ushort* __restrict__ Pb, const ushort* __restrict__ vt,
    ushort* __restrict__ yb)
{
  __shared__ __align__(16) ushort Ps[64][72];
  __shared__ __align__(16) ushort Vs[64][72];
  const int tid = threadIdx.x;
  const int w = tid >> 6, lane = tid & 63;
  const int bx = blockIdx.x;
  const int h = bx & 15;
  const int cc = 7 - (bx >> 4);          // heavy chunks first
  const int g = h >> 1;
  const int i0 = cc * 64;
  const int rbw = w * 16;
  const int lr = lane & 15, lk = (lane >> 4) * 8;
  f32x4 acc[4] = {};
  f32x4 accl = {};                       // row sums via ones-MFMA

  bf16x8 ones;
#pragma unroll
  for (int e = 0; e < 8; ++e) ones[e] = (short)0x3F80;   // bf16 1.0

  const int srow = tid >> 2, scol = (tid & 3) * 16;
  for (int jt = 0; jt <= cc; ++jt) {
    const int j0 = jt * 64;
    __syncthreads();
    {
      const ushort* ps = &Pb[h * (TT * TT) + (i0 + srow) * 512 + j0 + scol];
      uint4 a0 = *reinterpret_cast<const uint4*>(ps);
      uint4 a1 = *reinterpret_cast<const uint4*>(ps + 8);
      const ushort* vs = &vt[g * 32768 + srow * 512 + j0 + scol];
      uint4 b0 = *reinterpret_cast<const uint4*>(vs);
      uint4 b1 = *reinterpret_cast<const uint4*>(vs + 8);
      *reinterpret_cast<uint4*>(&Ps[srow][scol]) = a0;
      *reinterpret_cast<uint4*>(&Ps[srow][scol + 8]) = a1;
      *reinterpret_cast<uint4*>(&Vs[srow][scol]) = b0;
      *reinterpret_cast<uint4*>(&Vs[srow][scol + 8]) = b1;
    }
    __syncthreads();
#pragma unroll
    for (int kk = 0; kk < 2; ++kk) {
      bf16x8 af = *reinterpret_cast<const bf16x8*>(&Ps[rbw + lr][kk * 32 + lk]);
      accl = __builtin_amdgcn_mfma_f32_16x16x32_bf16(af, ones, accl, 0, 0, 0);
#pragma unroll
      for (int ni = 0; ni < 4; ++ni) {
        bf16x8 bg = *reinterpret_cast<const bf16x8*>(&Vs[ni * 16 + lr][kk * 32 + lk]);
        acc[ni] = __builtin_amdgcn_mfma_f32_16x16x32_bf16(af, bg, acc[ni], 0, 0, 0);
      }
    }
  }

  const int crow = (lane >> 4) * 4, ccol = lane & 15;
#pragma unroll
  for (int r = 0; r < 4; ++r) {
    int i = i0 + rbw + crow + r;
    float linv = 1.0f / accl[r];
#pragma unroll
    for (int ni = 0; ni < 4; ++ni)
      yb[i * 1024 + h * 64 + ni * 16 + ccol] = f2bf(acc[ni][r] * linv);
  }
}

// ---------------------------------------------------------------------------
extern "C" void kernel_launch(void* const* d_in, const int* in_sizes, int n_in,
                              void* d_out, int out_size, void* d_ws, size_t ws_size,
                              hipStream_t stream) {
  const float* x    = (const float*)d_in[0];
  const float* cosb = (const float*)d_in[1];
  const float* sinb = (const float*)d_in[2];
  const float* Wq   = (const float*)d_in[3];
  const float* Wk   = (const float*)d_in[4];
  const float* Wv   = (const float*)d_in[5];
  const float* Wo   = (const float*)d_in[6];
  float* out = (float*)d_out;

  float* wsf = (float*)d_ws;
  float* qbuf  = wsf;                      // 512x1024 f32
  float* kbuf  = qbuf + TT * CC;           // 512x512  f32 (pre-rope)
  float* vbuf  = kbuf + TT * 512;          // 512x512  f32
  float* ktb   = vbuf + TT * 512;          // 8x64x512 f32 (normalized K^T)
  ushort* wsu = (ushort*)(ktb + 8 * 64 * 512);
  ushort* xb  = wsu;                       // 512x1024 bf16
  ushort* yb  = xb + TT * CC;              // 512x1024 bf16
  ushort* Pb  = yb + TT * CC;              // 16x512x512 bf16 (P matrix)
  ushort* vtb = Pb + NH * TT * TT;         // 8x64x512 bf16 (V^T)
  ushort* Wtq = vtb + 8 * 64 * 512;        // 1024x1024 bf16
  ushort* Wtk = Wtq + CC * CC;             // 512x1024 bf16
  ushort* Wtv = Wtk + 512 * CC;            // 512x1024 bf16
  ushort* Wto = Wtv + 512 * CC;            // 1024x1024 bf16

  prep_kernel<<<dim3(1024), 256, 0, stream>>>(x, Wq, Wk, Wv, Wo, xb, Wtq, Wtk, Wtv, Wto);
  qkv_mfma_kernel<<<dim3(32, 8), 256, 0, stream>>>(xb, Wtq, Wtk, Wtv, qbuf, kbuf, vbuf);
  rope_fused_kernel<<<dim3(2176), 256, 0, stream>>>(qbuf, kbuf, vbuf, cosb, sinb, ktb, vtb);
  score_kernel<<<dim3(576), 256, 0, stream>>>(qbuf, ktb, Pb);
  pv_kernel<<<dim3(128), 256, 0, stream>>>(Pb, vtb, yb);
  out_mfma_kernel<<<dim3(16, 8), 256, 0, stream>>>(yb, Wto, out);
}